// Round 5
// baseline (450.564 us; speedup 1.0000x reference)
//
#include <hip/hip_runtime.h>
#include <cstdint>

// SpikeFP64Sqrt: rows of 64 float pulses (MSB-first fp64 bits) -> sqrt via
// exponent-halving guess + 12 IEEE fp64 Newton iterations -> pulses out.
//
// R3 post-mortem: 2x32 batched loads cut kernel 189 -> ~133us, but batch-1
// loads issue only after batch-0 ballots -> second exposed HBM stall/wave.
// R4: (1) single 64-deep load batch (progressive vmcnt waits -> one initial
// stall, then pure streaming); (2) non-temporal output stores so the
// write stream doesn't evict the input from the 256MiB L3 between timed
// iterations (R2 FETCH_SIZE already showed L3 absorbing half the input).
// R4b: __builtin_nontemporal_store needs a native vector type, not HIP float4.

#pragma clang fp contract(off)   // no FMA contraction anywhere (bit-exact fp64)

typedef float f32x4 __attribute__((ext_vector_type(4)));

static constexpr uint64_t kSqrt2Mant = 1865452045155277ULL;
static constexpr uint64_t kNanBits   = 0x7FF8000000000000ULL;
static constexpr uint64_t kInfBits   = 0x7FF0000000000000ULL;
static constexpr uint64_t kMantMask  = 0xFFFFFFFFFFFFFULL;

__global__ __launch_bounds__(256) void spike_fp64_sqrt_kernel(
    const float* __restrict__ x, float* __restrict__ out, int rows) {
  const int lane   = threadIdx.x & 63;
  const int waveId = (int)blockIdx.x * 4 + (threadIdx.x >> 6);
  const long long waveRow0 = (long long)waveId * 64;
  const int col = lane ^ 63;   // lane j loads pulse (63-j): ballot bit j == MSB-first bit j

  // ---- pack: 64 rows per wave; all 64 loads in flight before any ballot ----
  uint64_t u = 0;
  const bool fullWave = (waveRow0 + 64) <= (long long)rows;
  if (fullWave) {
    const float* base = x + waveRow0 * 64 + col;
    float v[64];
#pragma unroll
    for (int k = 0; k < 64; ++k) v[k] = base[(size_t)k * 64];   // 64 outstanding loads
#pragma unroll
    for (int k = 0; k < 64; ++k) {
      unsigned long long m = __ballot(v[k] > 0.5f);
      if (lane == k) u = m;                                     // v_writelane x2
    }
  } else {
#pragma unroll
    for (int rr = 0; rr < 64; ++rr) {
      const long long row = waveRow0 + rr;
      float v = (row < (long long)rows) ? x[row * 64 + col] : 0.0f;
      unsigned long long m = __ballot(v > 0.5f);
      if (lane == rr) u = m;
    }
  }

  // ---- per-lane fp64 sqrt, bit-exact vs reference ----
  const double f = __longlong_as_double((long long)u);

  const int e_x    = (int)((u >> 52) & 0x7FF);
  const int e_real = e_x - 1023;                       // 11-bit two's complement
  const long long e_half = ((long long)e_real) >> 1;   // arithmetic shift = floor/2
  const uint64_t mant = ((e_real & 1) != 0) ? kSqrt2Mant : 0ULL;
  const uint64_t ybits = (((uint64_t)(e_half + 1023)) << 52) | mant;
  double y = __longlong_as_double((long long)ybits);

#pragma unroll
  for (int it = 0; it < 12; ++it) {
    y = 0.5 * (y + f / y);                             // IEEE fp64, no contraction
  }

  uint64_t r = (uint64_t)__double_as_longlong(y);
  const bool is_neg    = (u >> 63) != 0;
  const bool m_any     = (u & kMantMask) != 0;
  const bool e_all_one = (e_x == 0x7FF);
  const bool e_is_zero = (e_x == 0);
  if (is_neg) r = kNanBits;                            // same override order as ref
  if (e_all_one && m_any) r = kNanBits;
  if (e_all_one && !m_any && !is_neg) r = kInfBits;
  if (e_is_zero && !m_any) r = 0ULL;

  // ---- unpack: 4 rows / iteration, non-temporal 16B stores ----
  const long long rl = (long long)r;
#pragma unroll
  for (int j = 0; j < 16; ++j) {
    const int srcRow = 4 * j + (lane >> 4);            // 0..63 within the wave
    const uint64_t b = (uint64_t)__shfl(rl, srcRow, 64);
    const int c0 = (lane & 15) * 4;                    // column of float4
    f32x4 o;
    o.x = (float)((b >> (63 - c0)) & 1ULL);
    o.y = (float)((b >> (62 - c0)) & 1ULL);
    o.z = (float)((b >> (61 - c0)) & 1ULL);
    o.w = (float)((b >> (60 - c0)) & 1ULL);
    const long long row = waveRow0 + srcRow;
    if (row < (long long)rows) {
      __builtin_nontemporal_store(o, reinterpret_cast<f32x4*>(out + row * 64 + c0));
    }
  }
}

extern "C" void kernel_launch(void* const* d_in, const int* in_sizes, int n_in,
                              void* d_out, int out_size, void* d_ws, size_t ws_size,
                              hipStream_t stream) {
  const float* x = (const float*)d_in[0];
  float* out = (float*)d_out;
  const int rows = in_sizes[0] / 64;                   // 64 pulses per fp64
  const int rowsPerBlock = 256;                        // 4 waves * 64 rows
  const int grid = (rows + rowsPerBlock - 1) / rowsPerBlock;
  spike_fp64_sqrt_kernel<<<grid, 256, 0, stream>>>(x, out, rows);
}

// Round 6
// 431.527 us; speedup vs baseline: 1.0441x; 1.0441x over previous
//
#include <hip/hip_runtime.h>
#include <cstdint>

// SpikeFP64Sqrt: rows of 64 float pulses (MSB-first fp64 bits) -> sqrt via
// exponent-halving guess + 12 IEEE fp64 Newton iterations -> pulses out.
//
// R5 post-mortem: MLP 4 -> 28+ on the per-row dword loads bought only 25us
// (189 -> 164); nothing saturated (VALU 16%, HBM 31%). The wall is the pack
// mechanism: 64 VMEM instrs + 64 ballot->SGPR->select cross-lane chains in
// strict vmcnt-consume order + 32 dynamic bpermutes. R6 restructure:
//   - global_load_lds width=16: 16 instrs stage the 16KB wave tile into LDS
//     (no VGPR round trip, no consume ordering).
//   - per-lane pack from LDS via XOR-swizzled ds_read_b128 (2-way bank
//     aliasing = free, no padding needed -> compatible with the linear
//     lane*16 layout global_load_lds requires). Bit = (bits(f)>>23)&1
//     (pulses are exact 0.0f/1.0f).
//   - no ballot / writelane / shfl anywhere.
//   - output transpose via 64x8B LDS words (broadcast ds_read_b64, in-order
//     DS pipe within the wave), plain coalesced dwordx4 stores (nt stores
//     regressed ~20us in R5 -> reverted).

#pragma clang fp contract(off)   // no FMA contraction anywhere (bit-exact fp64)

typedef float    f32x4 __attribute__((ext_vector_type(4)));
typedef uint32_t u32x4 __attribute__((ext_vector_type(4)));

static constexpr uint64_t kSqrt2Mant = 1865452045155277ULL;
static constexpr uint64_t kNanBits   = 0x7FF8000000000000ULL;
static constexpr uint64_t kInfBits   = 0x7FF0000000000000ULL;
static constexpr uint64_t kMantMask  = 0xFFFFFFFFFFFFFULL;

__device__ __forceinline__ void load_lds16(const float* g, uint32_t* lds) {
  __builtin_amdgcn_global_load_lds(
      (const __attribute__((address_space(1))) void*)g,
      (__attribute__((address_space(3))) void*)lds,
      16 /*bytes per lane*/, 0 /*offset*/, 0 /*aux*/);
}

__global__ __launch_bounds__(128) void spike_fp64_sqrt_kernel(
    const float* __restrict__ x, float* __restrict__ out, int rows) {
  __shared__ uint32_t tile[2][4096];           // 16 KB per wave
  const int lane = threadIdx.x & 63;
  const int wv   = threadIdx.x >> 6;           // wave in block (0..1)
  const long long waveRow0 = ((long long)blockIdx.x * 2 + wv) * 64;
  uint32_t* wbuf = tile[wv];

  uint64_t u = 0;
  const bool fullWave = (waveRow0 + 64) <= (long long)rows;
  if (fullWave) {
    // ---- stage 16 KB (64 rows x 256 B) direct to LDS: 16 x 1KB segments ----
    const float* gbase = x + waveRow0 * 64 + lane * 4;   // lane-linear 16B
#pragma unroll
    for (int t = 0; t < 16; ++t) {
      load_lds16(gbase + t * 256, wbuf + t * 256);
    }
    asm volatile("s_waitcnt vmcnt(0)" ::: "memory");

    // ---- pack own row (lane i -> row i): swizzled b128 reads, no conflicts ----
    const int myRow = lane * 64;                         // dword offset of my row
#pragma unroll
    for (int t = 0; t < 16; ++t) {
      const int c = t ^ (lane & 15);                     // chunk swizzle
      u32x4 v = *(const u32x4*)(wbuf + myRow + c * 4);   // pulses 4c..4c+3
      const uint32_t b0 = (v.x >> 23) & 1u;              // 1.0f has exp bit23=1
      const uint32_t b1 = (v.y >> 23) & 1u;
      const uint32_t b2 = (v.z >> 23) & 1u;
      const uint32_t b3 = (v.w >> 23) & 1u;
      const uint32_t nib = (b0 << 3) | (b1 << 2) | (b2 << 1) | b3;
      u |= (uint64_t)nib << (60 - 4 * c);                // pulse p -> bit 63-p
    }
  } else {
    // tail fallback (unused at this size): serial ballot pack
#pragma unroll 4
    for (int rr = 0; rr < 64; ++rr) {
      const long long row = waveRow0 + rr;
      float v = (row < (long long)rows) ? x[row * 64 + (lane ^ 63)] : 0.0f;
      unsigned long long m = __ballot(v > 0.5f);
      if (lane == rr) u = m;
    }
  }

  // ---- per-lane fp64 sqrt, bit-exact vs reference ----
  const double f = __longlong_as_double((long long)u);

  const int e_x    = (int)((u >> 52) & 0x7FF);
  const int e_real = e_x - 1023;                       // 11-bit two's complement
  const long long e_half = ((long long)e_real) >> 1;   // arithmetic shift = floor/2
  const uint64_t mant = ((e_real & 1) != 0) ? kSqrt2Mant : 0ULL;
  const uint64_t ybits = (((uint64_t)(e_half + 1023)) << 52) | mant;
  double y = __longlong_as_double((long long)ybits);

#pragma unroll
  for (int it = 0; it < 12; ++it) {
    y = 0.5 * (y + f / y);                             // IEEE fp64, no contraction
  }

  uint64_t r = (uint64_t)__double_as_longlong(y);
  const bool is_neg    = (u >> 63) != 0;
  const bool m_any     = (u & kMantMask) != 0;
  const bool e_all_one = (e_x == 0x7FF);
  const bool e_is_zero = (e_x == 0);
  if (is_neg) r = kNanBits;                            // same override order as ref
  if (e_all_one && m_any) r = kNanBits;
  if (e_all_one && !m_any && !is_neg) r = kInfBits;
  if (e_is_zero && !m_any) r = 0ULL;

  // ---- unpack: result words through LDS (same wave, in-order DS pipe) ----
  if (fullWave) {
    ((uint64_t*)wbuf)[lane] = r;                       // ds_write_b64
#pragma unroll
    for (int t = 0; t < 16; ++t) {
      const int srcRow = 4 * t + (lane >> 4);          // 0..63 within the wave
      const uint64_t w = ((const uint64_t*)wbuf)[srcRow];   // broadcast read
      const int c0 = (lane & 15) * 4;                  // pulse index of o.x
      const uint32_t nib = (uint32_t)(w >> (60 - c0)) & 0xFu;
      f32x4 o;
      o.x = (float)((nib >> 3) & 1u);
      o.y = (float)((nib >> 2) & 1u);
      o.z = (float)((nib >> 1) & 1u);
      o.w = (float)(nib & 1u);
      *(f32x4*)(out + (waveRow0 + srcRow) * 64 + c0) = o;   // coalesced 1KB/instr
    }
  } else {
    const long long rl = (long long)r;
#pragma unroll 4
    for (int j = 0; j < 16; ++j) {
      const int srcRow = 4 * j + (lane >> 4);
      const uint64_t b = (uint64_t)__shfl(rl, srcRow, 64);
      const int c0 = (lane & 15) * 4;
      f32x4 o;
      o.x = (float)((b >> (63 - c0)) & 1ULL);
      o.y = (float)((b >> (62 - c0)) & 1ULL);
      o.z = (float)((b >> (61 - c0)) & 1ULL);
      o.w = (float)((b >> (60 - c0)) & 1ULL);
      const long long row = waveRow0 + srcRow;
      if (row < (long long)rows) {
        *(f32x4*)(out + row * 64 + c0) = o;
      }
    }
  }
}

extern "C" void kernel_launch(void* const* d_in, const int* in_sizes, int n_in,
                              void* d_out, int out_size, void* d_ws, size_t ws_size,
                              hipStream_t stream) {
  const float* x = (const float*)d_in[0];
  float* out = (float*)d_out;
  const int rows = in_sizes[0] / 64;                   // 64 pulses per fp64
  const int rowsPerBlock = 128;                        // 2 waves * 64 rows
  const int grid = (rows + rowsPerBlock - 1) / rowsPerBlock;
  spike_fp64_sqrt_kernel<<<grid, 128, 0, stream>>>(x, out, rows);
}

// Round 7
// 419.747 us; speedup vs baseline: 1.0734x; 1.0281x over previous
//
#include <hip/hip_runtime.h>
#include <cstdint>

// SpikeFP64Sqrt: rows of 64 float pulses (MSB-first fp64 bits) -> sqrt via
// exponent-halving guess + 12 IEEE fp64 Newton iterations -> pulses out.
//
// R6 post-mortem: LDS-pack (R6) == ballot-pack (R3) == ~145us. The wall is
// not the pack mechanism; it's the mixed 16KB-read + 16KB-write stream per
// wave (~3.3 TB/s effective touch vs 6.3-6.5 for pure streams), plus L3
// thrash: the 268MB poisoned output almost exactly fills the 256MiB L3 and
// fights the input reads (FETCH_SIZE showed exactly half the input from HBM).
//
// R7: two-kernel split through an 8MB u64 word buffer in d_ws.
//   kernel1: pack (ballot) + fp64 sqrt -> words. Reads 268MB (NON-TEMPORAL:
//            read-once, keep out of L3), writes 8MB. Nearly pure read stream.
//   kernel2: words -> pulse expansion. Reads 8MB (cache-resident),
//            writes 268MB coalesced dwordx4. Fill-shaped pure write stream.
// Separate rocprof rows for read side vs write side localize the 2x gap.

#pragma clang fp contract(off)   // no FMA contraction anywhere (bit-exact fp64)

typedef float f32x4 __attribute__((ext_vector_type(4)));

static constexpr uint64_t kSqrt2Mant = 1865452045155277ULL;
static constexpr uint64_t kNanBits   = 0x7FF8000000000000ULL;
static constexpr uint64_t kInfBits   = 0x7FF0000000000000ULL;
static constexpr uint64_t kMantMask  = 0xFFFFFFFFFFFFFULL;

// ---------------- kernel 1: pulses -> packed u64 -> sqrt -> word buffer ----
__global__ __launch_bounds__(256) void spike_sqrt_pack_kernel(
    const float* __restrict__ x, uint64_t* __restrict__ w, int rows) {
  const int lane   = threadIdx.x & 63;
  const int waveId = (int)blockIdx.x * 4 + (threadIdx.x >> 6);
  const long long waveRow0 = (long long)waveId * 64;
  const int col = lane ^ 63;   // lane j reads pulse (63-j): ballot bit j == MSB-first bit j

  uint64_t u = 0;
  const bool fullWave = (waveRow0 + 64) <= (long long)rows;
  if (fullWave) {
    const float* base = x + waveRow0 * 64 + col;
#pragma unroll
    for (int b = 0; b < 2; ++b) {
      float v[32];
#pragma unroll
      for (int k = 0; k < 32; ++k)   // 32 nt loads in flight (read-once stream)
        v[k] = __builtin_nontemporal_load(base + (size_t)(b * 32 + k) * 64);
#pragma unroll
      for (int k = 0; k < 32; ++k) {
        unsigned long long m = __ballot(v[k] > 0.5f);
        if (lane == b * 32 + k) u = m;
      }
    }
  } else {
#pragma unroll 4
    for (int rr = 0; rr < 64; ++rr) {
      const long long row = waveRow0 + rr;
      float v = (row < (long long)rows) ? x[row * 64 + col] : 0.0f;
      unsigned long long m = __ballot(v > 0.5f);
      if (lane == rr) u = m;
    }
  }

  // ---- per-lane fp64 sqrt, bit-exact vs reference ----
  const double f = __longlong_as_double((long long)u);

  const int e_x    = (int)((u >> 52) & 0x7FF);
  const int e_real = e_x - 1023;                       // 11-bit two's complement
  const long long e_half = ((long long)e_real) >> 1;   // arithmetic shift = floor/2
  const uint64_t mant = ((e_real & 1) != 0) ? kSqrt2Mant : 0ULL;
  const uint64_t ybits = (((uint64_t)(e_half + 1023)) << 52) | mant;
  double y = __longlong_as_double((long long)ybits);

#pragma unroll
  for (int it = 0; it < 12; ++it) {
    y = 0.5 * (y + f / y);                             // IEEE fp64, no contraction
  }

  uint64_t r = (uint64_t)__double_as_longlong(y);
  const bool is_neg    = (u >> 63) != 0;
  const bool m_any     = (u & kMantMask) != 0;
  const bool e_all_one = (e_x == 0x7FF);
  const bool e_is_zero = (e_x == 0);
  if (is_neg) r = kNanBits;                            // same override order as ref
  if (e_all_one && m_any) r = kNanBits;
  if (e_all_one && !m_any && !is_neg) r = kInfBits;
  if (e_is_zero && !m_any) r = 0ULL;

  const long long myRow = waveRow0 + lane;
  if (myRow < (long long)rows) w[myRow] = r;           // coalesced dwordx2, 512B/wave
}

// ---------------- kernel 2: word buffer -> pulse expansion (write stream) --
__global__ __launch_bounds__(256) void spike_unpack_kernel(
    const uint64_t* __restrict__ w, float* __restrict__ out, int rows) {
  const int lane   = threadIdx.x & 63;
  const int waveId = (int)blockIdx.x * 4 + (threadIdx.x >> 6);
  const long long waveRow0 = (long long)waveId * 64;

  const long long myRow = waveRow0 + lane;
  const uint64_t r = (myRow < (long long)rows) ? w[myRow] : 0ULL;
  const long long rl = (long long)r;

#pragma unroll
  for (int t = 0; t < 16; ++t) {
    const int srcRow = 4 * t + (lane >> 4);            // 0..63 within the wave
    const uint64_t b = (uint64_t)__shfl(rl, srcRow, 64);
    const int c0 = (lane & 15) * 4;                    // pulse index of o.x
    f32x4 o;
    o.x = (float)((b >> (63 - c0)) & 1ULL);
    o.y = (float)((b >> (62 - c0)) & 1ULL);
    o.z = (float)((b >> (61 - c0)) & 1ULL);
    o.w = (float)((b >> (60 - c0)) & 1ULL);
    const long long row = waveRow0 + srcRow;
    if (row < (long long)rows) {
      *reinterpret_cast<f32x4*>(out + row * 64 + c0) = o;   // 1KB per instr
    }
  }
}

extern "C" void kernel_launch(void* const* d_in, const int* in_sizes, int n_in,
                              void* d_out, int out_size, void* d_ws, size_t ws_size,
                              hipStream_t stream) {
  const float* x = (const float*)d_in[0];
  float* out = (float*)d_out;
  uint64_t* words = (uint64_t*)d_ws;                   // rows*8 bytes (8MB) scratch
  const int rows = in_sizes[0] / 64;                   // 64 pulses per fp64
  const int rowsPerBlock = 256;                        // 4 waves * 64 rows
  const int grid = (rows + rowsPerBlock - 1) / rowsPerBlock;
  spike_sqrt_pack_kernel<<<grid, 256, 0, stream>>>(x, words, rows);
  spike_unpack_kernel<<<grid, 256, 0, stream>>>(words, out, rows);
}